// Round 4
// baseline (803.930 us; speedup 1.0000x reference)
//
#include <hip/hip_runtime.h>
#include <hip/hip_bf16.h>

// DecoderBlock: h_t = tanh(x_t @ U + h_{t-1} @ V + b)
// BZ=256, SEQ=512, IN=HID=256. fp32 in/out.
//
// FUSED, m=16 design: 16 WGs, each owns 16 batch rows (recurrence independent
// per row) and runs all 512 steps. Every 16x16x32 bf16 MFMA is fully useful:
// A = [16 batch rows] x [k-slice] of x_t / h_{t-1} (bf16 in LDS, padded
// stride 264 to spread banks), B = register-resident bf16 U/V frags
// (128 VGPRs), C rows = batch rows. Wave w owns cols [32w,32w+32).
// One barrier per step; x prefetched 2 steps deep in registers (unroll x2).

#define SEQn 512
#define HIDn 256
#define LSTR 264   // padded LDS row stride (elements); 132 words -> bank spread

typedef __attribute__((ext_vector_type(4))) float  floatx4;
typedef __attribute__((ext_vector_type(8))) short  short8;

__device__ __forceinline__ short f2bf(float f) {
    __hip_bfloat16 h = __float2bfloat16(f);
    return *reinterpret_cast<short*>(&h);
}

// ---------------------------------------------------------------------------
// Pack U and V (fp32 [256][256]) into bf16 B-frag order:
// ws[((kb*4+q)*256 + col)*8 + j] = W[kb*32 + q*8 + j][col].  128 KB each.
// ---------------------------------------------------------------------------
__global__ void prep_W(const float* __restrict__ U, const float* __restrict__ V,
                       short* __restrict__ wsU, short* __restrict__ wsV) {
    int idx = blockIdx.x * 256 + threadIdx.x;   // 0..8191
    int col = idx & 255;
    int q   = (idx >> 8) & 3;
    int kb  = idx >> 10;
    int k0  = kb * 32 + q * 8;
    short8 cu, cv;
    #pragma unroll
    for (int j = 0; j < 8; j++) {
        cu[j] = f2bf(U[(size_t)(k0 + j) * 256 + col]);
        cv[j] = f2bf(V[(size_t)(k0 + j) * 256 + col]);
    }
    *(short8*)(wsU + (size_t)idx * 8) = cu;
    *(short8*)(wsV + (size_t)idx * 8) = cv;
}

// ---------------------------------------------------------------------------
// Fused recurrence, 16 batch rows per WG. 512 threads = 8 waves.
// ---------------------------------------------------------------------------
__global__ __launch_bounds__(512, 2)
void rnn_fused16(const float* __restrict__ enc, const float* __restrict__ x,
                 const float* __restrict__ bias,
                 const short* __restrict__ wsU, const short* __restrict__ wsV,
                 float* __restrict__ out)
{
    __shared__ short xb[2][16][LSTR];   // bf16 x_t rows, double-buffered
    __shared__ short hb[2][16][LSTR];   // bf16 h rows, double-buffered

    const int tid = threadIdx.x;
    const int w   = tid >> 6;        // wave 0..7: cols [32w, 32w+32)
    const int l   = tid & 63;
    const int lr  = l & 15;          // A m-row / B n-col within tile
    const int q   = l >> 4;          // quad
    const int b0  = blockIdx.x * 16; // batch-row group base

    // Register-resident weight B-frags: uf/vf[kb][nt] (128 VGPRs).
    short8 uf[8][2], vf[8][2];
    #pragma unroll
    for (int kb = 0; kb < 8; kb++)
        #pragma unroll
        for (int nt = 0; nt < 2; nt++) {
            size_t base = ((size_t)(kb * 4 + q) * 256 + 32 * w + 16 * nt + lr) * 8;
            uf[kb][nt] = *(const short8*)(wsU + base);
            vf[kb][nt] = *(const short8*)(wsV + base);
        }

    // staging role: thread handles row srow, 8 cols at scol
    const int srow = tid >> 5;         // 0..15
    const int scol = (tid & 31) * 8;   // 0..248
    const float* xrowT = x + (size_t)(b0 + srow) * SEQn * HIDn + scol;

    float* outDec = out + (size_t)65536;

    // init: xb[0] = bf16(x[.,0,.]), hb[0] = bf16(enc rows)
    {
        float4 a0 = *(const float4*)(xrowT);
        float4 a1 = *(const float4*)(xrowT + 4);
        short8 xs = {f2bf(a0.x), f2bf(a0.y), f2bf(a0.z), f2bf(a0.w),
                     f2bf(a1.x), f2bf(a1.y), f2bf(a1.z), f2bf(a1.w)};
        *(short8*)&xb[0][srow][scol] = xs;
        const float* ep = enc + (size_t)(b0 + srow) * HIDn + scol;
        float4 e0 = *(const float4*)(ep);
        float4 e1 = *(const float4*)(ep + 4);
        short8 hs = {f2bf(e0.x), f2bf(e0.y), f2bf(e0.z), f2bf(e0.w),
                     f2bf(e1.x), f2bf(e1.y), f2bf(e1.z), f2bf(e1.w)};
        *(short8*)&hb[0][srow][scol] = hs;
    }
    // 2-deep register prefetch: pA = x[1], pB = x[2]
    float4 pA0 = *(const float4*)(xrowT + HIDn);
    float4 pA1 = *(const float4*)(xrowT + HIDn + 4);
    float4 pB0 = *(const float4*)(xrowT + 2 * HIDn);
    float4 pB1 = *(const float4*)(xrowT + 2 * HIDn + 4);
    __syncthreads();

    const int   c0    = 32 * w + lr;
    const int   c1    = c0 + 16;
    const float bias0 = bias[c0];
    const float bias1 = bias[c1];

#define STEP(T, CUR, PX0, PX1)                                                \
  {                                                                           \
    const int nxt = 1 - (CUR);                                                \
    floatx4 acc0 = (floatx4){0.f, 0.f, 0.f, 0.f};                             \
    floatx4 acc1 = (floatx4){0.f, 0.f, 0.f, 0.f};                             \
    _Pragma("unroll")                                                         \
    for (int kb = 0; kb < 8; kb++) {                                          \
      short8 xa = *(const short8*)&xb[CUR][lr][kb * 32 + q * 8];              \
      short8 ha = *(const short8*)&hb[CUR][lr][kb * 32 + q * 8];              \
      acc0 = __builtin_amdgcn_mfma_f32_16x16x32_bf16(xa, uf[kb][0], acc0, 0, 0, 0); \
      acc1 = __builtin_amdgcn_mfma_f32_16x16x32_bf16(xa, uf[kb][1], acc1, 0, 0, 0); \
      acc0 = __builtin_amdgcn_mfma_f32_16x16x32_bf16(ha, vf[kb][0], acc0, 0, 0, 0); \
      acc1 = __builtin_amdgcn_mfma_f32_16x16x32_bf16(ha, vf[kb][1], acc1, 0, 0, 0); \
    }                                                                         \
    /* stage x[T+1] (held in PX regs) into xb[nxt] */                         \
    {                                                                         \
      short8 xs = {f2bf(PX0.x), f2bf(PX0.y), f2bf(PX0.z), f2bf(PX0.w),        \
                   f2bf(PX1.x), f2bf(PX1.y), f2bf(PX1.z), f2bf(PX1.w)};       \
      *(short8*)&xb[nxt][srow][scol] = xs;                                    \
    }                                                                         \
    /* refill PX with x[T+3] (clamped) — 2 steps of latency slack */          \
    {                                                                         \
      int tl = ((T) + 3 < SEQn) ? (T) + 3 : SEQn - 1;                         \
      const float* p = xrowT + (size_t)tl * HIDn;                             \
      PX0 = *(const float4*)p;                                                \
      PX1 = *(const float4*)(p + 4);                                          \
    }                                                                         \
    /* epilogue: C row = 4q+r (batch row in group), col = c0/c1 */            \
    _Pragma("unroll")                                                         \
    for (int r = 0; r < 4; r++) {                                             \
      float s0 = acc0[r] + bias0;                                             \
      float s1 = acc1[r] + bias1;                                             \
      float h0v = 1.f - 2.f / (__expf(2.f * s0) + 1.f);                       \
      float h1v = 1.f - 2.f / (__expf(2.f * s1) + 1.f);                       \
      int row = 4 * q + r;                                                    \
      hb[nxt][row][c0] = f2bf(h0v);                                           \
      hb[nxt][row][c1] = f2bf(h1v);                                           \
      float* po = outDec + ((size_t)(b0 + row) * SEQn + (T)) * HIDn;          \
      po[c0] = h0v;                                                           \
      po[c1] = h1v;                                                           \
    }                                                                         \
    __syncthreads();                                                          \
  }

    for (int t = 0; t < SEQn; t += 2) {
        STEP(t,     0, pA0, pA1)
        STEP(t + 1, 1, pB0, pB1)
    }
#undef STEP

    // encoder passthrough (last, enabling d_out-as-weight-scratch fallback)
    {
        const float* ep = enc + (size_t)(b0 + srow) * HIDn + scol;
        float4 e0 = *(const float4*)(ep);
        float4 e1 = *(const float4*)(ep + 4);
        float* po = out + (size_t)(b0 + srow) * HIDn + scol;
        *(float4*)po       = e0;
        *(float4*)(po + 4) = e1;
    }
}

extern "C" void kernel_launch(void* const* d_in, const int* in_sizes, int n_in,
                              void* d_out, int out_size, void* d_ws, size_t ws_size,
                              hipStream_t stream) {
    const float* enc  = (const float*)d_in[0];   // [256,256]
    const float* x    = (const float*)d_in[1];   // [256,512,256]
    const float* U    = (const float*)d_in[2];   // [256,256]
    const float* V    = (const float*)d_in[3];   // [256,256]
    const float* bias = (const float*)d_in[4];   // [256]
    float* out = (float*)d_out;                  // 65536 + 33554432 floats

    // bf16 B-frag scratch: 128 KB (U) + 128 KB (V). Fallback: encoder region
    // of d_out (weights read at WG start; encoder region written only at end).
    short *wsU, *wsV;
    if (ws_size >= 262144) {
        wsU = (short*)d_ws;
        wsV = wsU + 65536;
    } else {
        wsU = (short*)out;
        wsV = wsU + 65536;
    }

    prep_W<<<32, 256, 0, stream>>>(U, V, wsU, wsV);
    rnn_fused16<<<16, 512, 0, stream>>>(enc, x, bias, wsU, wsV, out);
}